// Round 8
// baseline (600.247 us; speedup 1.0000x reference)
//
#include <hip/hip_runtime.h>
#include <hip/hip_bf16.h>
#include <hip/hip_cooperative_groups.h>

namespace cg = cooperative_groups;

// Problem constants (from reference setup_inputs)
#define M_TOK 8192
#define N_OUT 4096
#define K_IN  4096

#define SPARSIFY_BLOCKS 2048
#define CONVX_BLOCKS    4096
#define PREP_BLOCKS     (SPARSIFY_BLOCKS + CONVX_BLOCKS)

#define NBLK 256        // cooperative grid: 1 block/CU, co-resident

typedef __attribute__((ext_vector_type(8))) __bf16 bf16x8;
typedef __attribute__((ext_vector_type(4))) float f32x4;
typedef __attribute__((ext_vector_type(8))) unsigned short u16x8;

__device__ __forceinline__ unsigned short f2bf(float f) {
    return __builtin_bit_cast(unsigned short, (__bf16)f);
}

// 2:4 soft-threshold of one float4 group -> 4 bf16 + sumsq accumulation
__device__ __forceinline__ void st24(const float4 g, unsigned short* o,
                                     float& dsq, float& ssq) {
    float a0 = fabsf(g.x), a1 = fabsf(g.y), a2 = fabsf(g.z), a3 = fabsf(g.w);
    float lo1 = fminf(a0, a1), hi1 = fmaxf(a0, a1);
    float lo2 = fminf(a2, a3), hi2 = fmaxf(a2, a3);
    float t = fminf(fmaxf(lo1, lo2), fminf(hi1, hi2));
    float s0 = (a0 > t) ? copysignf(a0 - t, g.x) : 0.0f;
    float s1 = (a1 > t) ? copysignf(a1 - t, g.y) : 0.0f;
    float s2 = (a2 > t) ? copysignf(a2 - t, g.z) : 0.0f;
    float s3 = (a3 > t) ? copysignf(a3 - t, g.w) : 0.0f;
    dsq += g.x * g.x + g.y * g.y + g.z * g.z + g.w * g.w;
    ssq += s0 * s0 + s1 * s1 + s2 * s2 + s3 * s3;
    o[0] = f2bf(s0); o[1] = f2bf(s1); o[2] = f2bf(s2); o[3] = f2bf(s3);
}

// ---------------------------------------------------------------------------
// GEMM building blocks (R6 schedule, best measured 242.9 us, shared by both
// the fused kernel and the fallback kernel).
// ---------------------------------------------------------------------------
#define BM 256
#define BN 256
#define BK 64
#define NT (K_IN / BK)   // 64 K-tiles

#define GBAR() do { asm volatile("" ::: "memory"); \
                    __builtin_amdgcn_s_barrier();  \
                    asm volatile("" ::: "memory"); } while (0)

#define STAGE1(GP, OFF, HT, TAU, LI)                                           \
  do {                                                                         \
    const int _t = (TAU);                                                      \
    unsigned short* _d = smem + ((_t & 1) << 15) + (((HT) >> 1) << 14) +       \
                         (((HT) & 1) << 13) + ((LI) << 12) + (wv << 9);        \
    __builtin_amdgcn_global_load_lds(                                          \
        (const __attribute__((address_space(1))) void*)((GP) + (OFF) + _t * 64),\
        (__attribute__((address_space(3))) void*)_d, 16, 0, 0);                \
  } while (0)

#define STRIPQ(MIB, NA, NB, BA, BB)                                            \
  do {                                                                         \
    __builtin_amdgcn_s_setprio(1);                                             \
    _Pragma("unroll")                                                          \
    for (int mi = 0; mi < 4; ++mi) {                                           \
      acc[(MIB) + mi][NA] = __builtin_amdgcn_mfma_f32_16x16x32_bf16(           \
          aL[mi][0], BA[0], acc[(MIB) + mi][NA], 0, 0, 0);                     \
      acc[(MIB) + mi][NB] = __builtin_amdgcn_mfma_f32_16x16x32_bf16(           \
          aL[mi][0], BB[0], acc[(MIB) + mi][NB], 0, 0, 0);                     \
    }                                                                          \
    _Pragma("unroll")                                                          \
    for (int mi = 0; mi < 4; ++mi) {                                           \
      acc[(MIB) + mi][NA] = __builtin_amdgcn_mfma_f32_16x16x32_bf16(           \
          aL[mi][1], BA[1], acc[(MIB) + mi][NA], 0, 0, 0);                     \
      acc[(MIB) + mi][NB] = __builtin_amdgcn_mfma_f32_16x16x32_bf16(           \
          aL[mi][1], BB[1], acc[(MIB) + mi][NB], 0, 0, 0);                     \
    }                                                                          \
    __builtin_amdgcn_s_setprio(0);                                             \
  } while (0)

// Full GEMM tile: prologue + 64-tile K-loop (R6 schedule: reads 12/4/8/0,
// 2 stages/phase, vmcnt(8)@P1, vmcnt(6)@P3, tail drains 2->0).
#define GEMM_TILE_BODY()                                                       \
    asm volatile("s_waitcnt vmcnt(0)" ::: "memory");                           \
    GBAR();                                                                    \
    STAGE1(A, offA[0][0], 0, 0, 0);  STAGE1(A, offA[1][0], 1, 0, 0);           \
    STAGE1(B, offB[0][0], 2, 0, 0);  STAGE1(B, offB[0][1], 2, 0, 1);           \
    STAGE1(B, offB[1][0], 3, 0, 0);  STAGE1(B, offB[1][1], 3, 0, 1);           \
    STAGE1(A, offA[0][1], 0, 0, 1);  STAGE1(A, offA[1][1], 1, 0, 1);           \
    STAGE1(B, offB[0][0], 2, 1, 0);  STAGE1(B, offB[0][1], 2, 1, 1);           \
    STAGE1(B, offB[1][0], 3, 1, 0);  STAGE1(B, offB[1][1], 3, 1, 1);           \
    asm volatile("s_waitcnt vmcnt(6)" ::: "memory");                           \
    GBAR();                                                                    \
    for (int t = 0; t < NT; ++t) {                                             \
        const unsigned bufo = (unsigned)((t & 1) << 15);                       \
        const unsigned ba = bufo + aoff;                                       \
        const unsigned bb = bufo + boff;                                       \
        bf16x8 aL[4][2], b0[2], b1[2], b2[2], b3[2];                           \
        _Pragma("unroll")                                                      \
        for (int mi = 0; mi < 4; ++mi) {                                       \
            aL[mi][0] = *(const bf16x8*)(smem + ba + (mi << 10));              \
            aL[mi][1] = *(const bf16x8*)(smem + ba + (mi << 10) + 512);        \
        }                                                                      \
        b0[0] = *(const bf16x8*)(smem + bb);                                   \
        b0[1] = *(const bf16x8*)(smem + bb + 512);                             \
        b1[0] = *(const bf16x8*)(smem + bb + 1024);                            \
        b1[1] = *(const bf16x8*)(smem + bb + 1536);                            \
        if (t + 1 < NT) {                                                      \
            STAGE1(A, offA[0][0], 0, t + 1, 0);                                \
            STAGE1(A, offA[1][0], 1, t + 1, 0);                                \
        }                                                                      \
        asm volatile("s_waitcnt lgkmcnt(8)" ::: "memory");                     \
        GBAR();                                                                \
        STRIPQ(0, 0, 1, b0, b1);                                               \
        GBAR();                                                                \
        b2[0] = *(const bf16x8*)(smem + bb + 2048);                            \
        b2[1] = *(const bf16x8*)(smem + bb + 2560);                            \
        b3[0] = *(const bf16x8*)(smem + bb + 3072);                            \
        b3[1] = *(const bf16x8*)(smem + bb + 3584);                            \
        if (t + 1 < NT) {                                                      \
            STAGE1(A, offA[0][1], 0, t + 1, 1);                                \
            STAGE1(A, offA[1][1], 1, t + 1, 1);                                \
        }                                                                      \
        GBAR();                                                                \
        STRIPQ(0, 2, 3, b2, b3);                                               \
        if (t == NT - 1) asm volatile("s_waitcnt vmcnt(0)" ::: "memory");      \
        else             asm volatile("s_waitcnt vmcnt(8)" ::: "memory");      \
        GBAR();                                                                \
        _Pragma("unroll")                                                      \
        for (int mi = 0; mi < 4; ++mi) {                                       \
            aL[mi][0] = *(const bf16x8*)(smem + ba + ((4 + mi) << 10));        \
            aL[mi][1] = *(const bf16x8*)(smem + ba + ((4 + mi) << 10) + 512);  \
        }                                                                      \
        if (t + 2 < NT) {                                                      \
            STAGE1(B, offB[0][0], 2, t + 2, 0);                                \
            STAGE1(B, offB[0][1], 2, t + 2, 1);                                \
        }                                                                      \
        GBAR();                                                                \
        STRIPQ(4, 2, 3, b2, b3);                                               \
        GBAR();                                                                \
        if (t + 2 < NT) {                                                      \
            STAGE1(B, offB[1][0], 3, t + 2, 0);                                \
            STAGE1(B, offB[1][1], 3, t + 2, 1);                                \
        }                                                                      \
        GBAR();                                                                \
        STRIPQ(4, 0, 1, b0, b1);                                               \
        if (t < NT - 2)       asm volatile("s_waitcnt vmcnt(6)" ::: "memory"); \
        else if (t == NT - 2) asm volatile("s_waitcnt vmcnt(2)" ::: "memory"); \
        else                  asm volatile("s_waitcnt vmcnt(0)" ::: "memory"); \
        GBAR();                                                                \
    }

// ---------------------------------------------------------------------------
// FUSED cooperative kernel: prep (all blocks) -> grid.sync -> scale -> GEMM
// (each block runs 2 output tiles: bswz and bswz+256, same N-panel so the
// 2 MB B-panel is L2-warm for the second tile). vmcnt(0) at rep start since
// C-stores share the vmcnt counter with staging loads.
// ---------------------------------------------------------------------------
__global__ __launch_bounds__(512, 2) void fused_kernel(
        const float* __restrict__ x,
        const float* __restrict__ w,
        const float* __restrict__ bias,
        unsigned short* __restrict__ xb,
        unsigned short* __restrict__ wsb,
        float* __restrict__ pdc,    // [NBLK]
        float* __restrict__ psc,    // [NBLK]
        float* __restrict__ C) {
    __shared__ __align__(16) unsigned short smem[65536];  // 128 KiB

    const int tid  = threadIdx.x;          // 0..511
    const int lane = tid & 63;
    const int wv   = tid >> 6;             // 0..7
    const int wm   = wv >> 2;
    const int wn   = wv & 3;
    const int quad = lane >> 4;
    const int l16  = lane & 15;

    // ===================== PREP PHASE =====================
    {
        const int gthr = blockIdx.x * 512 + tid;     // 0..131071
        float dsq = 0.0f, ssq = 0.0f;
        // W sparsify: 2,097,152 u16x8-units / 131,072 threads = 16 (exact)
#pragma unroll 4
        for (int it = 0; it < 16; ++it) {
            const int pid = gthr + it * (NBLK * 512);
            const float4 gA = ((const float4*)w)[2 * pid];
            const float4 gB = ((const float4*)w)[2 * pid + 1];
            u16x8 o;
            st24(gA, (unsigned short*)&o, dsq, ssq);
            st24(gB, ((unsigned short*)&o) + 4, dsq, ssq);
            ((u16x8*)wsb)[pid] = o;
        }
        // x conversion: 4,194,304 units / 131,072 = 32 (exact)
#pragma unroll 4
        for (int it = 0; it < 32; ++it) {
            const int i = gthr + it * (NBLK * 512);
            const float4 v0 = ((const float4*)x)[2 * i];
            const float4 v1 = ((const float4*)x)[2 * i + 1];
            u16x8 o;
            o[0] = f2bf(v0.x); o[1] = f2bf(v0.y);
            o[2] = f2bf(v0.z); o[3] = f2bf(v0.w);
            o[4] = f2bf(v1.x); o[5] = f2bf(v1.y);
            o[6] = f2bf(v1.z); o[7] = f2bf(v1.w);
            ((u16x8*)xb)[i] = o;
        }
        // block-reduce partial sumsqs -> pdc/psc[blockIdx.x]
        for (int off = 32; off > 0; off >>= 1) {
            dsq += __shfl_down(dsq, off);
            ssq += __shfl_down(ssq, off);
        }
        float* fs = (float*)smem;
        if (lane == 0) { fs[wv] = dsq; fs[8 + wv] = ssq; }
        __syncthreads();
        if (tid == 0) {
            float a = 0.0f, b = 0.0f;
#pragma unroll
            for (int k = 0; k < 8; ++k) { a += fs[k]; b += fs[8 + k]; }
            pdc[blockIdx.x] = a;
            psc[blockIdx.x] = b;
        }
        __syncthreads();
    }
    __threadfence();            // device-scope release of wsb/xb/pdc/psc
    cg::this_grid().sync();
    __threadfence();            // acquire side

    // ===================== SCALE =====================
    float scale;
    {
        float d = 0.0f, s = 0.0f;
        if (tid < NBLK) { d = pdc[tid]; s = psc[tid]; }
        for (int off = 32; off > 0; off >>= 1) {
            d += __shfl_down(d, off);
            s += __shfl_down(s, off);
        }
        float* fs = (float*)smem;
        if (lane == 0) { fs[wv] = d; fs[8 + wv] = s; }
        __syncthreads();
        float dt = 0.0f, st = 0.0f;
#pragma unroll
        for (int k = 0; k < 8; ++k) { dt += fs[k]; st += fs[8 + k]; }
        st = fmaxf(st, 1e-12f);
        scale = fminf(fmaxf(sqrtf(dt / st), 0.1f), 10.0f);
        __syncthreads();        // protect fs before staging reuses LDS
    }

    // ===================== GEMM: 2 tiles/block =====================
    const unsigned short* A = xb;
    const unsigned short* B = wsb;

    // per-thread staging map (idx -> logical row/col, inverse st_16x32 swz)
    int rowm[2], colm[2];
#pragma unroll
    for (int i = 0; i < 2; ++i) {
        const int idx = i * 512 + tid;
        const int s   = idx >> 6;
        const int bby = (idx & 63) << 4;
        const int bl  = bby ^ (((bby >> 9) & 1) << 5);
        rowm[i] = (s >> 1) * 16 + (bl >> 6);
        colm[i] = (s & 1) * 32 + ((bl & 63) >> 1);
    }
    const unsigned innerE =
        (unsigned)(((l16 * 64 + quad * 16) ^ (((l16 >> 3) & 1) << 5)) >> 1);
    const unsigned aoff = (unsigned)(wm << 13) + innerE;
    const unsigned boff = 16384u + ((wn >> 1) << 13) + ((wn & 1) << 12) + innerE;

    // XCD-aware: consecutive bids round-robin XCDs; bswz gives each XCD a
    // contiguous 32-tile chunk. Rep 1 = bswz+256 (same N-panel).
    const int bswz = (blockIdx.x & 7) * 32 + (blockIdx.x >> 3);

#pragma unroll 1
    for (int rep = 0; rep < 2; ++rep) {
        const int T  = bswz + rep * NBLK;            // 0..511
        const int m0 = (T >> 4) * BM;
        const int n0 = (T & 15) * BN;

        unsigned offA[2][2], offB[2][2];
#pragma unroll
        for (int i = 0; i < 2; ++i)
#pragma unroll
            for (int h = 0; h < 2; ++h) {
                offA[h][i] = (unsigned)(m0 + h * 128 + rowm[i]) * K_IN + colm[i];
                offB[h][i] = (unsigned)(n0 + h * 128 + rowm[i]) * K_IN + colm[i];
            }

        f32x4 acc[8][4] = {};

        GEMM_TILE_BODY()

        // epilogue: scale + bias, fp32 store (no LDS)
#pragma unroll
        for (int p = 0; p < 4; ++p) {
            const int col = n0 + wn * 64 + p * 16 + l16;
            const float bv = bias[col];
#pragma unroll
            for (int mi = 0; mi < 8; ++mi) {
#pragma unroll
                for (int r = 0; r < 4; ++r) {
                    const int row = m0 + wm * 128 + mi * 16 + quad * 4 + r;
                    C[(size_t)row * N_OUT + col] = scale * acc[mi][p][r] + bv;
                }
            }
        }
    }
}

// ---------------------------------------------------------------------------
// FALLBACK path (verbatim R6 two-kernel pipeline) — used only if the
// cooperative launch is rejected by the runtime.
// ---------------------------------------------------------------------------
__global__ __launch_bounds__(256) void prep_kernel(
        const float* __restrict__ w,
        const float* __restrict__ x,
        unsigned short* __restrict__ wsb,
        unsigned short* __restrict__ xb,
        float* __restrict__ pd,
        float* __restrict__ ps) {
    if (blockIdx.x < SPARSIFY_BLOCKS) {
        const int base = blockIdx.x * 256 + threadIdx.x;
        float dsq = 0.0f, ssq = 0.0f;
#pragma unroll
        for (int it = 0; it < 4; ++it) {
            const int pid = base + it * (SPARSIFY_BLOCKS * 256);
            const float4 gA = ((const float4*)w)[2 * pid];
            const float4 gB = ((const float4*)w)[2 * pid + 1];
            u16x8 o;
            st24(gA, (unsigned short*)&o, dsq, ssq);
            st24(gB, ((unsigned short*)&o) + 4, dsq, ssq);
            ((u16x8*)wsb)[pid] = o;
        }
        for (int off = 32; off > 0; off >>= 1) {
            dsq += __shfl_down(dsq, off);
            ssq += __shfl_down(ssq, off);
        }
        __shared__ float sd[4], ss[4];
        int lane = threadIdx.x & 63, wv = threadIdx.x >> 6;
        if (lane == 0) { sd[wv] = dsq; ss[wv] = ssq; }
        __syncthreads();
        if (threadIdx.x == 0) {
            pd[blockIdx.x] = sd[0] + sd[1] + sd[2] + sd[3];
            ps[blockIdx.x] = ss[0] + ss[1] + ss[2] + ss[3];
        }
    } else {
        const int base = (blockIdx.x - SPARSIFY_BLOCKS) * 256 + threadIdx.x;
#pragma unroll
        for (int it = 0; it < 4; ++it) {
            const int i = base + it * (CONVX_BLOCKS * 256);
            const float4 v0 = ((const float4*)x)[2 * i];
            const float4 v1 = ((const float4*)x)[2 * i + 1];
            u16x8 o;
            o[0] = f2bf(v0.x); o[1] = f2bf(v0.y);
            o[2] = f2bf(v0.z); o[3] = f2bf(v0.w);
            o[4] = f2bf(v1.x); o[5] = f2bf(v1.y);
            o[6] = f2bf(v1.z); o[7] = f2bf(v1.w);
            ((u16x8*)xb)[i] = o;
        }
    }
}

__global__ __launch_bounds__(512, 2) void gemm_8phase_kernel(
        const unsigned short* __restrict__ A,
        const unsigned short* __restrict__ B,
        const float* __restrict__ bias,
        const float* __restrict__ pd,
        const float* __restrict__ ps,
        float* __restrict__ C) {
    __shared__ __align__(16) unsigned short smem[65536];

    const int tid  = threadIdx.x;
    const int lane = tid & 63;
    const int wv   = tid >> 6;
    const int wm   = wv >> 2;
    const int wn   = wv & 3;
    const int quad = lane >> 4;
    const int l16  = lane & 15;

    const int nwg = (M_TOK / BM) * (N_OUT / BN);          // 512
    const int swz = (blockIdx.x & 7) * (nwg >> 3) + (blockIdx.x >> 3);
    const int m0 = (swz >> 4) * BM;
    const int n0 = (swz & 15) * BN;

    unsigned offA[2][2], offB[2][2];
#pragma unroll
    for (int i = 0; i < 2; ++i) {
        const int idx = i * 512 + tid;
        const int s   = idx >> 6;
        const int bby = (idx & 63) << 4;
        const int bl  = bby ^ (((bby >> 9) & 1) << 5);
        const int row = (s >> 1) * 16 + (bl >> 6);
        const int col = (s & 1) * 32 + ((bl & 63) >> 1);
#pragma unroll
        for (int h = 0; h < 2; ++h) {
            offA[h][i] = (unsigned)(m0 + h * 128 + row) * K_IN + col;
            offB[h][i] = (unsigned)(n0 + h * 128 + row) * K_IN + col;
        }
    }
    const unsigned innerE =
        (unsigned)(((l16 * 64 + quad * 16) ^ (((l16 >> 3) & 1) << 5)) >> 1);
    const unsigned aoff = (unsigned)(wm << 13) + innerE;
    const unsigned boff = 16384u + ((wn >> 1) << 13) + ((wn & 1) << 12) + innerE;

    f32x4 acc[8][4] = {};

    GEMM_TILE_BODY()

    float d = 0.0f, s = 0.0f;
#pragma unroll
    for (int k = 0; k < SPARSIFY_BLOCKS / 512; ++k) {
        d += pd[tid + k * 512];
        s += ps[tid + k * 512];
    }
    for (int off = 32; off > 0; off >>= 1) {
        d += __shfl_down(d, off);
        s += __shfl_down(s, off);
    }
    float* fs = (float*)smem;
    if (lane == 0) { fs[wv] = d; fs[8 + wv] = s; }
    __syncthreads();
    float dt = 0.0f, st = 0.0f;
#pragma unroll
    for (int k = 0; k < 8; ++k) { dt += fs[k]; st += fs[8 + k]; }
    st = fmaxf(st, 1e-12f);
    const float scale = fminf(fmaxf(sqrtf(dt / st), 0.1f), 10.0f);

#pragma unroll
    for (int p = 0; p < 4; ++p) {
        const int col = n0 + wn * 64 + p * 16 + l16;
        const float bv = bias[col];
#pragma unroll
        for (int mi = 0; mi < 8; ++mi) {
#pragma unroll
            for (int r = 0; r < 4; ++r) {
                const int row = m0 + wm * 128 + mi * 16 + quad * 4 + r;
                C[(size_t)row * N_OUT + col] = scale * acc[mi][p][r] + bv;
            }
        }
    }
}

// ---------------------------------------------------------------------------
// Launch: cooperative fused kernel; fallback to R6 two-kernel path on error.
// ---------------------------------------------------------------------------
extern "C" void kernel_launch(void* const* d_in, const int* in_sizes, int n_in,
                              void* d_out, int out_size, void* d_ws, size_t ws_size,
                              hipStream_t stream) {
    const float* x      = (const float*)d_in[0];   // [8192][4096]
    const float* weight = (const float*)d_in[1];   // [4096][4096]
    const float* bias   = (const float*)d_in[2];   // [4096]
    float* out          = (float*)d_out;           // [8192][4096]

    char* ws = (char*)d_ws;
    float* pd_fb        = (float*)(ws + 1024);                // 2048 f (fallback)
    float* ps_fb        = (float*)(ws + 1024 + 8192);         // 2048 f
    float* pdc          = (float*)(ws + 20480);               // 256 f (fused)
    float* psc          = (float*)(ws + 21504);               // 256 f
    unsigned short* wsb = (unsigned short*)(ws + 32768);      // 32 MB bf16 W_s
    unsigned short* xb  = (unsigned short*)(ws + 32768 + (size_t)N_OUT * K_IN * 2); // 64 MB

    void* args[] = {(void*)&x, (void*)&weight, (void*)&bias,
                    (void*)&xb, (void*)&wsb, (void*)&pdc, (void*)&psc,
                    (void*)&out};
    hipError_t e = hipLaunchCooperativeKernel(
        reinterpret_cast<void*>(fused_kernel),
        dim3(NBLK), dim3(512), args, 0, stream);

    if (e != hipSuccess) {
        // Fallback: proven R6 two-kernel pipeline (242.9 us GEMM)
        prep_kernel<<<PREP_BLOCKS, 256, 0, stream>>>(weight, x, wsb, xb,
                                                     pd_fb, ps_fb);
        const int nwg = (M_TOK / BM) * (N_OUT / BN);   // 512
        gemm_8phase_kernel<<<dim3(nwg), dim3(512), 0, stream>>>(
            xb, wsb, bias, pd_fb, ps_fb, out);
    }
}

// Round 9
// 474.012 us; speedup vs baseline: 1.2663x; 1.2663x over previous
//
#include <hip/hip_runtime.h>
#include <hip/hip_bf16.h>

// Problem constants (from reference setup_inputs)
#define M_TOK 8192
#define N_OUT 4096
#define K_IN  4096

#define SPARSIFY_BLOCKS 2048
#define CONVX_BLOCKS    6144
#define PREP_BLOCKS     (SPARSIFY_BLOCKS + CONVX_BLOCKS)

typedef __attribute__((ext_vector_type(8))) __bf16 bf16x8;
typedef __attribute__((ext_vector_type(4))) float f32x4;

__device__ __forceinline__ unsigned short f2bf(float f) {
    return __builtin_bit_cast(unsigned short, (__bf16)f);
}

// ---------------------------------------------------------------------------
// Kernel 1 (fused prep): blocks [0,2048) soft-threshold 2:4 sparsify of W
// (fp32 -> bf16 W_s + per-block partial dense/sparse sumsq); blocks
// [2048,8192) convert x fp32 -> bf16. Independent streams, one launch.
// High occupancy (small LDS, 256 thr) — memory-bound phases need the TLP
// that the GEMM's 128 KiB LDS forbids (R8 lesson: fusing them 1-block/CU
// cost ~3x on prep).
// ---------------------------------------------------------------------------
__global__ __launch_bounds__(256) void prep_kernel(
        const float* __restrict__ w,
        const float* __restrict__ x,
        unsigned short* __restrict__ wsb,
        unsigned short* __restrict__ xb,
        float* __restrict__ pd,     // [SPARSIFY_BLOCKS] partial dense_sq
        float* __restrict__ ps,     // [SPARSIFY_BLOCKS] partial sparse_sq
        int ngroups, int n4) {
    if (blockIdx.x < SPARSIFY_BLOCKS) {
        const int stride = SPARSIFY_BLOCKS * 256;
        float dsq = 0.0f, ssq = 0.0f;
        for (int gid = blockIdx.x * 256 + threadIdx.x; gid < ngroups;
             gid += stride) {
            const float4 g = ((const float4*)w)[gid];
            float a0 = fabsf(g.x), a1 = fabsf(g.y);
            float a2 = fabsf(g.z), a3 = fabsf(g.w);
            float lo1 = fminf(a0, a1), hi1 = fmaxf(a0, a1);
            float lo2 = fminf(a2, a3), hi2 = fmaxf(a2, a3);
            float t = fminf(fmaxf(lo1, lo2), fminf(hi1, hi2));
            float s0 = (a0 > t) ? copysignf(a0 - t, g.x) : 0.0f;
            float s1 = (a1 > t) ? copysignf(a1 - t, g.y) : 0.0f;
            float s2 = (a2 > t) ? copysignf(a2 - t, g.z) : 0.0f;
            float s3 = (a3 > t) ? copysignf(a3 - t, g.w) : 0.0f;
            dsq += g.x * g.x + g.y * g.y + g.z * g.z + g.w * g.w;
            ssq += s0 * s0 + s1 * s1 + s2 * s2 + s3 * s3;
            ushort4 o;
            o.x = f2bf(s0); o.y = f2bf(s1); o.z = f2bf(s2); o.w = f2bf(s3);
            ((ushort4*)wsb)[gid] = o;
        }
        for (int off = 32; off > 0; off >>= 1) {
            dsq += __shfl_down(dsq, off);
            ssq += __shfl_down(ssq, off);
        }
        __shared__ float sd[4], ss[4];
        int lane = threadIdx.x & 63, wv = threadIdx.x >> 6;
        if (lane == 0) { sd[wv] = dsq; ss[wv] = ssq; }
        __syncthreads();
        if (threadIdx.x == 0) {
            pd[blockIdx.x] = sd[0] + sd[1] + sd[2] + sd[3];
            ps[blockIdx.x] = ss[0] + ss[1] + ss[2] + ss[3];
        }
    } else {
        const int stride = CONVX_BLOCKS * 256;
        for (int i = (blockIdx.x - SPARSIFY_BLOCKS) * 256 + threadIdx.x;
             i < n4; i += stride) {
            float4 v = ((const float4*)x)[i];
            ushort4 o;
            o.x = f2bf(v.x); o.y = f2bf(v.y); o.z = f2bf(v.z); o.w = f2bf(v.w);
            ((ushort4*)xb)[i] = o;
        }
    }
}

// ---------------------------------------------------------------------------
// Kernel 2: 256x256-tile 8-phase GEMM — faithful m201 schedule.
// Best-measured configuration of the session (472.6 us total, GEMM 242.4 us,
// MfmaUtil 49.3%, SQ_LDS_BANK_CONFLICT 0).
// C[M][N] = scale * (A[M][K] @ B[N][K]^T) + bias[N]
//
//  - BM=BN=256, BK=64, 8 waves (2M x 4N), per-wave output 128x64,
//    mfma_f32_16x16x32_bf16 (shape-matched to st_16x32 swizzle: each frag
//    read's 64 lanes cover one full 1024B subtile -> conflict-free; the
//    32x32 shape violates this, costs 2.5e7 conflicts and 2.8x time — R5).
//  - LDS 128 KiB: 2 buffers x (A 32 KiB + B 32 KiB), [16][32]-subtiled with
//    st_16x32 swizzle (byte ^= ((byte>>9)&1)<<5). global_load_lds writes
//    linearly; swizzle applied on per-lane GLOBAL source (involution) and on
//    ds_read byte address (rule #21: both-sides-or-neither).
//  - 4 phases per K-tile, one C-quadrant each; ds_reads 12/4/8/0; EXACTLY
//    2 global_load_lds issued per phase (the m196/m201 interleave lever):
//      P0: read a[0-3],b0,b1 (12; lgkmcnt(8) hint); stage A.l0s(t+1) -> Q00
//      P1: read b2,b3 (4);   stage A.l1s(t+1); vmcnt(8)            -> Q01
//      P2: read a[4-7] (8);  stage B.h0(t+2)                       -> Q11
//      P3:                   stage B.h1(t+2); vmcnt(6)             -> Q10
//    A half-tile load0 = rows 0-63 (used at P0), load1 = rows 64-127 (P2).
//    A stages (P0/P1) target the OTHER buffer; B stages (P2/P3) target the
//    current buffer (B reads done at P1's closing barrier). vmcnt(8)@P1
//    retires A.l1s needed by P2 (4 phases slack); vmcnt(6)@P3 retires next
//    tile's A.l0s + B halves. Never drains to 0 mid-loop; tail: 2 -> 0.
//  - Scale (norm-matching, clipped) computed per-block in the epilogue from
//    sparsify's partials (16 KB, L2-resident) — no separate scale kernel.
//  - Session plateau note: five structurally distinct schedules (lopsided
//    reads, balanced quadrants, static 2-tile unroll, b2/b3 hoist, fused
//    cooperative) all pin at MfmaUtil 49-51% / 242-247 us. Remaining known
//    levers (SRSRC, ds_read-imm patterns, sched_group_barrier) measured
//    null-isolated on this structure class.
// ---------------------------------------------------------------------------
#define BM 256
#define BN 256
#define BK 64
#define NT (K_IN / BK)   // 64 K-tiles

#define GBAR() do { asm volatile("" ::: "memory"); \
                    __builtin_amdgcn_s_barrier();  \
                    asm volatile("" ::: "memory"); } while (0)

// One 16-B-per-lane global_load_lds of half-tile quarter LI (0: rows 0-63,
// 1: rows 64-127). HT: 0=A.h0 1=A.h1 2=B.h0 3=B.h1 (literal). Element
// offsets: buf stride 32768, B region +16384, half +8192, LI +4096, wave +512.
#define STAGE1(GP, OFF, HT, TAU, LI)                                           \
  do {                                                                         \
    const int _t = (TAU);                                                      \
    unsigned short* _d = smem + ((_t & 1) << 15) + (((HT) >> 1) << 14) +       \
                         (((HT) & 1) << 13) + ((LI) << 12) + (wv << 9);        \
    __builtin_amdgcn_global_load_lds(                                          \
        (const __attribute__((address_space(1))) void*)((GP) + (OFF) + _t * 64),\
        (__attribute__((address_space(3))) void*)_d, 16, 0, 0);                \
  } while (0)

// One C-quadrant: rows MIB..MIB+3 (from aL), cols NA,NB (frags BA,BB). 16 MFMA.
#define STRIPQ(MIB, NA, NB, BA, BB)                                            \
  do {                                                                         \
    __builtin_amdgcn_s_setprio(1);                                             \
    _Pragma("unroll")                                                          \
    for (int mi = 0; mi < 4; ++mi) {                                           \
      acc[(MIB) + mi][NA] = __builtin_amdgcn_mfma_f32_16x16x32_bf16(           \
          aL[mi][0], BA[0], acc[(MIB) + mi][NA], 0, 0, 0);                     \
      acc[(MIB) + mi][NB] = __builtin_amdgcn_mfma_f32_16x16x32_bf16(           \
          aL[mi][0], BB[0], acc[(MIB) + mi][NB], 0, 0, 0);                     \
    }                                                                          \
    _Pragma("unroll")                                                          \
    for (int mi = 0; mi < 4; ++mi) {                                           \
      acc[(MIB) + mi][NA] = __builtin_amdgcn_mfma_f32_16x16x32_bf16(           \
          aL[mi][1], BA[1], acc[(MIB) + mi][NA], 0, 0, 0);                     \
      acc[(MIB) + mi][NB] = __builtin_amdgcn_mfma_f32_16x16x32_bf16(           \
          aL[mi][1], BB[1], acc[(MIB) + mi][NB], 0, 0, 0);                     \
    }                                                                          \
    __builtin_amdgcn_s_setprio(0);                                             \
  } while (0)

__global__ __launch_bounds__(512, 2) void gemm_8phase_kernel(
        const unsigned short* __restrict__ A,   // xb  bf16 [M][K]
        const unsigned short* __restrict__ B,   // wsb bf16 [N][K]
        const float* __restrict__ bias,         // [N]
        const float* __restrict__ pd,           // [SPARSIFY_BLOCKS]
        const float* __restrict__ ps,           // [SPARSIFY_BLOCKS]
        float* __restrict__ C) {                // [M][N]
    __shared__ __align__(16) unsigned short smem[65536];  // 128 KiB

    const int tid  = threadIdx.x;          // 0..511
    const int lane = tid & 63;
    const int wv   = tid >> 6;             // 0..7
    const int wm   = wv >> 2;              // 0..1  (M half)
    const int wn   = wv & 3;               // 0..3  (N quarter)
    const int quad = lane >> 4;
    const int l16  = lane & 15;

    // XCD-aware bijective swizzle: 512 wgs, 512 % 8 == 0
    const int nwg = (M_TOK / BM) * (N_OUT / BN);          // 512
    const int swz = (blockIdx.x & 7) * (nwg >> 3) + (blockIdx.x >> 3);
    const int m0 = (swz >> 4) * BM;                       // 32 M-tiles
    const int n0 = (swz & 15) * BN;                       // 16 N-tiles

    // --- per-thread staging source map (inverse st_16x32 swizzle) ---------
    unsigned offA[2][2], offB[2][2];       // [half][load_i], element offsets
#pragma unroll
    for (int i = 0; i < 2; ++i) {
        const int idx = i * 512 + tid;                    // 0..1023
        const int s   = idx >> 6;                         // subtile 0..15
        const int bby = (idx & 63) << 4;                  // byte in subtile
        const int bl  = bby ^ (((bby >> 9) & 1) << 5);    // logical byte
        const int row = (s >> 1) * 16 + (bl >> 6);        // 0..127
        const int col = (s & 1) * 32 + ((bl & 63) >> 1);  // 0,8,..,56
#pragma unroll
        for (int h = 0; h < 2; ++h) {
            offA[h][i] = (unsigned)(m0 + h * 128 + row) * K_IN + col;
            offB[h][i] = (unsigned)(n0 + h * 128 + row) * K_IN + col;
        }
    }

    // --- per-thread ds_read addressing (swizzled) -------------------------
    const unsigned innerE =
        (unsigned)(((l16 * 64 + quad * 16) ^ (((l16 >> 3) & 1) << 5)) >> 1);
    const unsigned aoff = (unsigned)(wm << 13) + innerE;
    const unsigned boff = 16384u + ((wn >> 1) << 13) + ((wn & 1) << 12) + innerE;

    f32x4 acc[8][4] = {};

    // --- prologue ---------------------------------------------------------
    // Issue order establishes the steady-state invariant at tile-0 entry:
    //   landed(6): A.l0s(0), B0(0), B1(0)   (everything P0/P1 of tile 0 reads)
    //   in-flight(6): A.l1s(0), B0(1), B1(1)
    STAGE1(A, offA[0][0], 0, 0, 0);  STAGE1(A, offA[1][0], 1, 0, 0);
    STAGE1(B, offB[0][0], 2, 0, 0);  STAGE1(B, offB[0][1], 2, 0, 1);
    STAGE1(B, offB[1][0], 3, 0, 0);  STAGE1(B, offB[1][1], 3, 0, 1);
    STAGE1(A, offA[0][1], 0, 0, 1);  STAGE1(A, offA[1][1], 1, 0, 1);
    STAGE1(B, offB[0][0], 2, 1, 0);  STAGE1(B, offB[0][1], 2, 1, 1);
    STAGE1(B, offB[1][0], 3, 1, 0);  STAGE1(B, offB[1][1], 3, 1, 1);
    asm volatile("s_waitcnt vmcnt(6)" ::: "memory");
    GBAR();

    for (int t = 0; t < NT; ++t) {
        const unsigned bufo = (unsigned)((t & 1) << 15);
        const unsigned ba = bufo + aoff;
        const unsigned bb = bufo + boff;
        bf16x8 aL[4][2], b0[2], b1[2], b2[2], b3[2];

        // ---- P0: read a[0-3] + b0,b1 (12); stage A.l0s(t+1); Q00 ---------
#pragma unroll
        for (int mi = 0; mi < 4; ++mi) {
            aL[mi][0] = *(const bf16x8*)(smem + ba + (mi << 10));
            aL[mi][1] = *(const bf16x8*)(smem + ba + (mi << 10) + 512);
        }
        b0[0] = *(const bf16x8*)(smem + bb);
        b0[1] = *(const bf16x8*)(smem + bb + 512);
        b1[0] = *(const bf16x8*)(smem + bb + 1024);
        b1[1] = *(const bf16x8*)(smem + bb + 1536);
        if (t + 1 < NT) {
            STAGE1(A, offA[0][0], 0, t + 1, 0);
            STAGE1(A, offA[1][0], 1, t + 1, 0);
        }
        asm volatile("s_waitcnt lgkmcnt(8)" ::: "memory");
        GBAR();
        STRIPQ(0, 0, 1, b0, b1);
        GBAR();

        // ---- P1: read b2,b3 (4); stage A.l1s(t+1); vmcnt(8); Q01 ---------
        b2[0] = *(const bf16x8*)(smem + bb + 2048);
        b2[1] = *(const bf16x8*)(smem + bb + 2560);
        b3[0] = *(const bf16x8*)(smem + bb + 3072);
        b3[1] = *(const bf16x8*)(smem + bb + 3584);
        if (t + 1 < NT) {
            STAGE1(A, offA[0][1], 0, t + 1, 1);
            STAGE1(A, offA[1][1], 1, t + 1, 1);
        }
        GBAR();
        STRIPQ(0, 2, 3, b2, b3);
        if (t == NT - 1) asm volatile("s_waitcnt vmcnt(0)" ::: "memory");
        else             asm volatile("s_waitcnt vmcnt(8)" ::: "memory");
        GBAR();

        // ---- P2: read a[4-7] (8); stage B.h0(t+2); Q11 -------------------
#pragma unroll
        for (int mi = 0; mi < 4; ++mi) {
            aL[mi][0] = *(const bf16x8*)(smem + ba + ((4 + mi) << 10));
            aL[mi][1] = *(const bf16x8*)(smem + ba + ((4 + mi) << 10) + 512);
        }
        if (t + 2 < NT) {
            STAGE1(B, offB[0][0], 2, t + 2, 0);
            STAGE1(B, offB[0][1], 2, t + 2, 1);
        }
        GBAR();
        STRIPQ(4, 2, 3, b2, b3);
        GBAR();

        // ---- P3: stage B.h1(t+2); Q10; vmcnt(6|2|0) ----------------------
        if (t + 2 < NT) {
            STAGE1(B, offB[1][0], 3, t + 2, 0);
            STAGE1(B, offB[1][1], 3, t + 2, 1);
        }
        GBAR();
        STRIPQ(4, 0, 1, b0, b1);
        if (t < NT - 2)       asm volatile("s_waitcnt vmcnt(6)" ::: "memory");
        else if (t == NT - 2) asm volatile("s_waitcnt vmcnt(2)" ::: "memory");
        else                  asm volatile("s_waitcnt vmcnt(0)" ::: "memory");
        GBAR();
    }

    // --- epilogue: per-block scale reduce (partials are L2-resident) ------
    float d = 0.0f, s = 0.0f;
#pragma unroll
    for (int k = 0; k < SPARSIFY_BLOCKS / 512; ++k) {
        d += pd[tid + k * 512];
        s += ps[tid + k * 512];
    }
    for (int off = 32; off > 0; off >>= 1) {
        d += __shfl_down(d, off);
        s += __shfl_down(s, off);
    }
    float* fs = (float*)smem;   // main loop done (post final GBAR), LDS free
    if (lane == 0) { fs[wv] = d; fs[8 + wv] = s; }
    __syncthreads();
    float dt = 0.0f, st = 0.0f;
#pragma unroll
    for (int k = 0; k < 8; ++k) { dt += fs[k]; st += fs[8 + k]; }
    st = fmaxf(st, 1e-12f);
    const float scale = fminf(fmaxf(sqrtf(dt / st), 0.1f), 10.0f);

    // --- scale + bias, fp32 store -----------------------------------------
#pragma unroll
    for (int p = 0; p < 4; ++p) {
        const int col = n0 + wn * 64 + p * 16 + l16;
        const float bv = bias[col];
#pragma unroll
        for (int mi = 0; mi < 8; ++mi) {
#pragma unroll
            for (int r = 0; r < 4; ++r) {
                const int row = m0 + wm * 128 + mi * 16 + quad * 4 + r;
                C[(size_t)row * N_OUT + col] = scale * acc[mi][p][r] + bv;
            }
        }
    }
}

// ---------------------------------------------------------------------------
// Launch: 2 kernels total (prep fused, scale folded into GEMM epilogue)
// ---------------------------------------------------------------------------
extern "C" void kernel_launch(void* const* d_in, const int* in_sizes, int n_in,
                              void* d_out, int out_size, void* d_ws, size_t ws_size,
                              hipStream_t stream) {
    const float* x      = (const float*)d_in[0];   // [8192][4096]
    const float* weight = (const float*)d_in[1];   // [4096][4096]
    const float* bias   = (const float*)d_in[2];   // [4096]
    float* out          = (float*)d_out;           // [8192][4096]

    char* ws = (char*)d_ws;
    float* pd           = (float*)(ws + 1024);                // 2048 floats
    float* psm          = (float*)(ws + 1024 + 4 * SPARSIFY_BLOCKS);
    unsigned short* wsb = (unsigned short*)(ws + 32768);      // 32 MB bf16 W_s
    unsigned short* xb  = (unsigned short*)(ws + 32768 + (size_t)N_OUT * K_IN * 2); // 64 MB bf16 x

    // 1) fused: sparsify W (+ partial sumsqs) || convert x -> bf16
    const int ngroups = N_OUT * K_IN / 4;   // 4,194,304
    const int n4 = M_TOK * K_IN / 4;        // 8,388,608
    prep_kernel<<<PREP_BLOCKS, 256, 0, stream>>>(weight, x, wsb, xb, pd, psm,
                                                 ngroups, n4);

    // 2) 256^2 8-phase GEMM + scale/bias epilogue
    const int nwg = (M_TOK / BM) * (N_OUT / BN);   // 512
    gemm_8phase_kernel<<<dim3(nwg), dim3(512), 0, stream>>>(xb, wsb, bias,
                                                            pd, psm, out);
}